// Round 1
// baseline (712.535 us; speedup 1.0000x reference)
//
#include <hip/hip_runtime.h>
#include <stdint.h>

#define NTOK 49
#define DIM  192
#define QKV3 576
#define NHEADS 6

typedef __attribute__((ext_vector_type(8))) short short8;
typedef __attribute__((ext_vector_type(4))) float f32x4;

__device__ __forceinline__ float bf2f(uint16_t u) {
    return __uint_as_float(((uint32_t)u) << 16);
}
__device__ __forceinline__ uint16_t f2bf(float f) {
    uint32_t u = __float_as_uint(f);
    return (uint16_t)((u + 0x7FFFu + ((u >> 16) & 1u)) >> 16);  // RNE
}
__device__ __forceinline__ uint32_t cvtpk_bf16(float a, float b) {
    uint32_t r;
    asm("v_cvt_pk_bf16_f32 %0, %1, %2" : "=v"(r) : "v"(a), "v"(b));
    return r;  // low 16 = bf16(a), high 16 = bf16(b)
}

// XOR-swizzled element offset for stride-192 bf16 tiles (16B granules).
__device__ __forceinline__ int swz(int row, int col) {
    return row * 192 + ((((col >> 3) ^ (row & 7)) << 3)) + (col & 7);
}
// Same for V^T tile: [d][64 tokens]
__device__ __forceinline__ int vswz(int d, int tok) {
    return d * 64 + ((((tok >> 3) ^ (d & 7)) << 3)) + (tok & 7);
}

// ---- prep: wqkvT[576][192] bf16, wprojT[192][192] bf16, biasT fp32 ----
// biasT layout [h][mt][nt][lane][i] now stores the TRANSPOSED C-frag:
//   value = bias_h[qt = mt*16 + (lane&15)][kt = nt*16 + (lane>>4)*4 + i]
#define NQ (QKV3 * DIM)          // 110592
#define NP (DIM * DIM)           // 36864
#define NB (NHEADS * 4 * 4 * 64 * 4)  // 24576
__global__ void prep_kernel(const float* __restrict__ wqkv,
                            const float* __restrict__ wproj,
                            const float* __restrict__ table,
                            uint16_t* __restrict__ ws) {
    int i = blockIdx.x * 256 + threadIdx.x;
    if (i < NQ) {
        int n = i / DIM, k = i - n * DIM;
        ws[i] = f2bf(wqkv[(size_t)k * QKV3 + n]);
    } else if (i < NQ + NP) {
        int j = i - NQ;
        int n = j / DIM, k = j - n * DIM;
        ws[NQ + j] = f2bf(wproj[(size_t)k * DIM + n]);
    } else if (i < NQ + NP + NB) {
        int e = i - NQ - NP;
        int ii   = e & 3;
        int lane = (e >> 2) & 63;
        int nt   = (e >> 8) & 3;
        int mt   = (e >> 10) & 3;
        int h    = e >> 12;
        int r = mt * 16 + (lane & 15);                 // qt (attn row)
        int c = nt * 16 + ((lane >> 4) << 2) + ii;     // kt (attn col)
        float val = 0.f;
        if (r < NTOK && c < NTOK) {
            int rm = r % 7, rd = r / 7, cm = c % 7, cd = c / 7;
            int bi = 13 * (rm - cm + 6) + (rd - cd + 6);
            val = table[bi * NHEADS + h];
        }
        ((float*)(ws + NQ + NP))[e] = val;
    }
}

// LDS element offsets (uint16 units). Total 40512 els = 81024 B -> 2 blocks/CU.
#define U_OFF   0        // x tile (49x192 swz) in phase A; per-wave pa (16x72) in phase B
#define QS_OFF  9408
#define KS_OFF  18816
#define VTA_OFF 28224    // 192x64
#define LDS_ELS 40512
#define PA_STR  72
#define R_STR   52       // fp32 reduction stride (52 dw -> conflict-free)

// ---- Phase A: register-blocked qkv GEMM. NCT col-tiles per wave;
// A-frags loaded once per kk, NCT*4 independent MFMAs per k-step. ----
template <int NCT, bool PRE>
__device__ __forceinline__ void phaseA_tiles(uint16_t* lds,
                                             const uint16_t* __restrict__ wqkvT,
                                             const float* __restrict__ w_qkv,
                                             const float* __restrict__ b_qkv,
                                             const int wave, const int q4, const int l16)
{
    const float SCALE = 0.17677669529663687f;
    f32x4 acc[NCT][4];
    #pragma unroll
    for (int j = 0; j < NCT; ++j)
        #pragma unroll
        for (int mt = 0; mt < 4; ++mt) acc[j][mt] = (f32x4){0.f, 0.f, 0.f, 0.f};

    #pragma unroll
    for (int kk = 0; kk < 6; ++kk) {
        short8 bf[NCT];
        #pragma unroll
        for (int j = 0; j < NCT; ++j) {
            const int col = (wave + 8 * j) * 16 + l16;
            if (PRE) {
                bf[j] = *(const short8*)&wqkvT[(size_t)col * DIM + kk * 32 + q4 * 8];
            } else {
                union { uint16_t u[8]; short8 v; } tb;
                const int k0 = kk * 32 + q4 * 8;
                #pragma unroll
                for (int jj = 0; jj < 8; ++jj)
                    tb.u[jj] = f2bf(w_qkv[(size_t)(k0 + jj) * QKV3 + col]);
                bf[j] = tb.v;
            }
        }
        #pragma unroll
        for (int mt = 0; mt < 4; ++mt) {
            short8 af = *(const short8*)&lds[U_OFF + swz(mt * 16 + l16, kk * 32 + q4 * 8)];
            #pragma unroll
            for (int j = 0; j < NCT; ++j)
                acc[j][mt] = __builtin_amdgcn_mfma_f32_16x16x32_bf16(af, bf[j], acc[j][mt], 0, 0, 0);
        }
    }

    #pragma unroll
    for (int j = 0; j < NCT; ++j) {
        const int ct  = wave + 8 * j;
        const int col = ct * 16 + l16;
        const float bias = b_qkv[col];
        if (col < DIM) {                       // Q (pre-scaled)
            #pragma unroll
            for (int mt = 0; mt < 4; ++mt)
                #pragma unroll
                for (int i = 0; i < 4; ++i) {
                    int tok = mt * 16 + q4 * 4 + i;
                    if (tok < NTOK)
                        lds[QS_OFF + swz(tok, col)] = f2bf((acc[j][mt][i] + bias) * SCALE);
                }
        } else if (col < 2 * DIM) {            // K
            const int kc = col - DIM;
            #pragma unroll
            for (int mt = 0; mt < 4; ++mt)
                #pragma unroll
                for (int i = 0; i < 4; ++i) {
                    int tok = mt * 16 + q4 * 4 + i;
                    if (tok < NTOK)
                        lds[KS_OFF + swz(tok, kc)] = f2bf(acc[j][mt][i] + bias);
                }
        } else {                               // V -> transposed [d][tok], b64-packed
            const int vc = col - 2 * DIM;
            #pragma unroll
            for (int mt = 0; mt < 4; ++mt) {
                const int tokb = mt * 16 + q4 * 4;
                union { uint16_t u[4]; ushort4 v; } pv;
                #pragma unroll
                for (int i = 0; i < 4; ++i) {
                    int tok = tokb + i;
                    pv.u[i] = (tok < NTOK) ? f2bf(acc[j][mt][i] + bias) : (uint16_t)0;
                }
                *(ushort4*)&lds[VTA_OFF + vc * 64 + ((((tokb >> 3) ^ (vc & 7)) << 3)) + (tokb & 7)] = pv.v;
            }
        }
    }
}

template <bool PRE>
__global__ __launch_bounds__(512, 4)
void winattn_mfma3(const float* __restrict__ x,
                   const float* __restrict__ mask, int nW, int nwin,
                   const float* __restrict__ w_qkv,
                   const float* __restrict__ b_qkv,
                   const float* __restrict__ w_proj,
                   const float* __restrict__ b_proj,
                   const float* __restrict__ table,
                   const uint16_t* __restrict__ wpre,
                   float* __restrict__ out)
{
    __shared__ __align__(16) uint16_t lds[LDS_ELS];

    const int t    = threadIdx.x;
    const int wave = t >> 6;
    const int lane = t & 63;
    const int q4   = lane >> 4;
    const int l16  = lane & 15;

    const uint16_t* wqkvT  = wpre;
    const uint16_t* wprojT = wpre + NQ;
    const float*    biasT  = (const float*)(wpre + NQ + NP);

    // ---- prologue: prefetch window 0's x into registers ----
    int w = blockIdx.x;
    float4 xf[5];
    {
        const float4* xb = (const float4*)(x + (size_t)w * (NTOK * DIM));
        #pragma unroll
        for (int j = 0; j < 5; ++j) {
            int i = t + 512 * j; if (i > 2351) i = 2351;
            xf[j] = xb[i];
        }
    }

    for (;;) {
        const float* maskw = mask + (size_t)(w % nW) * (NTOK * NTOK);
        float* ob = out + (size_t)w * (NTOK * DIM);
        int wnext = w + (int)gridDim.x;
        if (wnext >= nwin) wnext = w;

        // ---------- stage x regs -> swizzled bf16 LDS tile ----------
        #pragma unroll
        for (int j = 0; j < 5; ++j) {
            int i = t + 512 * j;
            if (i < 2352) {
                int e = i * 4, row = e / DIM, col = e - row * DIM;
                union { uint16_t u[4]; ushort4 v; } s;
                s.u[0] = f2bf(xf[j].x); s.u[1] = f2bf(xf[j].y);
                s.u[2] = f2bf(xf[j].z); s.u[3] = f2bf(xf[j].w);
                *(ushort4*)&lds[U_OFF + swz(row, col)] = s.v;
            }
        }
        __syncthreads();   // S1

        // ---------- Phase A ----------
        if (wave < 4) phaseA_tiles<5, PRE>(lds, wqkvT, w_qkv, b_qkv, wave, q4, l16);
        else          phaseA_tiles<4, PRE>(lds, wqkvT, w_qkv, b_qkv, wave, q4, l16);
        __syncthreads();   // S2

        // ---------- Phase B: attention (P^T softmax), zero barriers ----------
        const int mt    = wave & 3;
        const int hbase = (wave >> 2) * 3;
        uint16_t* paw = &lds[U_OFF + wave * (16 * PA_STR)];
        const int qt = mt * 16 + l16;
        const int qa = (qt < NTOK) ? qt : (NTOK - 1);

        f32x4 pacc[12];
        #pragma unroll
        for (int nt = 0; nt < 12; ++nt) pacc[nt] = (f32x4){0.f, 0.f, 0.f, 0.f};

        for (int hi = 0; hi < 3; ++hi) {
            const int h = hbase + hi;
            // --- QK^T swapped: lg[nt][i] = S[kt = nt*16+q4*4+i][qt = mt*16+l16] ---
            short8 bq = *(const short8*)&lds[QS_OFF + swz(qt, h * 32 + q4 * 8)];
            f32x4 lg[4];
            #pragma unroll
            for (int nt = 0; nt < 4; ++nt) {
                short8 ak = *(const short8*)&lds[KS_OFF + swz(nt * 16 + l16, h * 32 + q4 * 8)];
                f32x4 z = (f32x4){0.f, 0.f, 0.f, 0.f};
                lg[nt] = __builtin_amdgcn_mfma_f32_16x16x32_bf16(ak, bq, z, 0, 0, 0);
            }
            // --- + rel-pos bias (transposed layout) + mask ---
            #pragma unroll
            for (int nt = 0; nt < 4; ++nt) {
                if (PRE) {
                    f32x4 bb = *(const f32x4*)&biasT[(((h * 4 + mt) * 4 + nt) * 64 + lane) * 4];
                    #pragma unroll
                    for (int i = 0; i < 4; ++i) {
                        int kt = nt * 16 + q4 * 4 + i;
                        int ka = (kt < NTOK) ? kt : (NTOK - 1);
                        lg[nt][i] += bb[i] + maskw[qa * NTOK + ka];
                    }
                } else {
                    #pragma unroll
                    for (int i = 0; i < 4; ++i) {
                        int kt = nt * 16 + q4 * 4 + i;
                        int ka = (kt < NTOK) ? kt : (NTOK - 1);
                        int rm = qa % 7, rd = qa / 7, cm = ka % 7, cd = ka / 7;
                        int bi = 13 * (rm - cm + 6) + (rd - cd + 6);
                        lg[nt][i] += table[bi * NHEADS + h] + maskw[qa * NTOK + ka];
                    }
                }
            }
            // --- softmax: row is lane-local over regs + 2 shfls across q4 groups ---
            float m = lg[0][0];
            #pragma unroll
            for (int nt = 0; nt < 3; ++nt)
                #pragma unroll
                for (int i = 0; i < 4; ++i) m = fmaxf(m, lg[nt][i]);
            if (q4 == 0) m = fmaxf(m, lg[3][0]);      // kt == 48 only
            m = fmaxf(m, __shfl_xor(m, 16));
            m = fmaxf(m, __shfl_xor(m, 32));
            float s = 0.f;
            #pragma unroll
            for (int nt = 0; nt < 3; ++nt)
                #pragma unroll
                for (int i = 0; i < 4; ++i) { lg[nt][i] = __expf(lg[nt][i] - m); s += lg[nt][i]; }
            float e30 = (q4 == 0) ? __expf(lg[3][0] - m) : 0.f;   // zero kt>=49: no NaN leak
            s += e30;
            s += __shfl_xor(s, 16);
            s += __shfl_xor(s, 32);
            const float inv = 1.f / s;
            // --- pack P rows -> paw[qt_local][kt], 4 x b64 writes ---
            #pragma unroll
            for (int nt = 0; nt < 3; ++nt) {
                uint32_t lo = cvtpk_bf16(lg[nt][0] * inv, lg[nt][1] * inv);
                uint32_t hi = cvtpk_bf16(lg[nt][2] * inv, lg[nt][3] * inv);
                uint32_t* dst = (uint32_t*)&paw[l16 * PA_STR + nt * 16 + q4 * 4];
                dst[0] = lo; dst[1] = hi;
            }
            {
                uint32_t lo = cvtpk_bf16(e30 * inv, 0.f);
                uint32_t* dst = (uint32_t*)&paw[l16 * PA_STR + 48 + q4 * 4];
                dst[0] = lo; dst[1] = 0u;
            }
            asm volatile("" ::: "memory");   // in-order LDS within wave

            // --- PV: out tile 16x32 ---
            f32x4 ov[2];
            ov[0] = (f32x4){0.f, 0.f, 0.f, 0.f};
            ov[1] = (f32x4){0.f, 0.f, 0.f, 0.f};
            #pragma unroll
            for (int kk = 0; kk < 2; ++kk) {
                short8 ap = *(const short8*)&paw[l16 * PA_STR + kk * 32 + q4 * 8];
                #pragma unroll
                for (int n2 = 0; n2 < 2; ++n2) {
                    short8 bv = *(const short8*)&lds[VTA_OFF + vswz(h * 32 + n2 * 16 + l16,
                                                                    kk * 32 + q4 * 8)];
                    ov[n2] = __builtin_amdgcn_mfma_f32_16x16x32_bf16(ap, bv, ov[n2], 0, 0, 0);
                }
            }
            // --- transpose out-tile through the same private scratch ---
            asm volatile("" ::: "memory");
            #pragma unroll
            for (int n2 = 0; n2 < 2; ++n2)
                #pragma unroll
                for (int i = 0; i < 4; ++i)
                    paw[(q4 * 4 + i) * PA_STR + n2 * 16 + l16] = f2bf(ov[n2][i]);
            asm volatile("" ::: "memory");

            // --- proj partial: acc += os_h(16x32) @ wproj[h-slice](32x192) ---
            short8 ap2 = *(const short8*)&paw[l16 * PA_STR + q4 * 8];
            #pragma unroll
            for (int nt = 0; nt < 12; ++nt) {
                short8 bw;
                if (PRE) {
                    bw = *(const short8*)&wprojT[(size_t)(nt * 16 + l16) * DIM + h * 32 + q4 * 8];
                } else {
                    union { uint16_t u[8]; short8 v; } tb;
                    int k0 = h * 32 + q4 * 8;
                    #pragma unroll
                    for (int j = 0; j < 8; ++j)
                        tb.u[j] = f2bf(w_proj[(size_t)(k0 + j) * DIM + nt * 16 + l16]);
                    bw = tb.v;
                }
                pacc[nt] = __builtin_amdgcn_mfma_f32_16x16x32_bf16(ap2, bw, pacc[nt], 0, 0, 0);
            }
        }

        // ---- prefetch next window's x (latency hides under phase C) ----
        {
            const float4* xb = (const float4*)(x + (size_t)wnext * (NTOK * DIM));
            #pragma unroll
            for (int j = 0; j < 5; ++j) {
                int i = t + 512 * j; if (i > 2351) i = 2351;
                xf[j] = xb[i];
            }
        }
        __syncthreads();   // S3: all B done; qs/ks/vta/pa dead

        // ---------- Phase C: cross-wave-pair reduction + writeout ----------
        // R lives at QS_OFF.. so it cannot collide with next iteration's x-stage (U).
        float* R = (float*)&lds[QS_OFF];
        if (wave >= 4) {
            float* rw = R + (size_t)(mt * 64 + lane) * R_STR;
            #pragma unroll
            for (int nt = 0; nt < 12; ++nt)
                *(f32x4*)(rw + nt * 4) = pacc[nt];
        }
        __syncthreads();   // S4
        if (wave < 4) {
            const float* rr = R + (size_t)(mt * 64 + lane) * R_STR;
            #pragma unroll
            for (int nt = 0; nt < 12; ++nt) {
                f32x4 other = *(const f32x4*)(rr + nt * 4);
                const int c = nt * 16 + l16;
                const float bp = b_proj[c];
                #pragma unroll
                for (int i = 0; i < 4; ++i) {
                    const int r = mt * 16 + q4 * 4 + i;
                    if (r < NTOK) ob[r * DIM + c] = pacc[nt][i] + other[i] + bp;
                }
            }
        }

        if (wnext == w) break;
        w = wnext;
    }
}

extern "C" void kernel_launch(void* const* d_in, const int* in_sizes, int n_in,
                              void* d_out, int out_size, void* d_ws, size_t ws_size,
                              hipStream_t stream) {
    const float* x      = (const float*)d_in[0];
    const float* mask   = (const float*)d_in[1];
    const float* w_qkv  = (const float*)d_in[2];
    const float* b_qkv  = (const float*)d_in[3];
    const float* w_proj = (const float*)d_in[4];
    const float* b_proj = (const float*)d_in[5];
    const float* table  = (const float*)d_in[6];
    float* out = (float*)d_out;

    const int nblocks = in_sizes[0] / (NTOK * DIM);   // 4096 windows
    const int nW      = in_sizes[1] / (NTOK * NTOK);  // 64
    const size_t WS_NEED = (size_t)(NQ + NP) * 2 + (size_t)NB * 4;  // 393216 B

    int grid = nblocks < 512 ? nblocks : 512;         // persistent: 2 blocks/CU, 8 windows each

    if (ws_size >= WS_NEED && d_ws != nullptr) {
        uint16_t* wpre = (uint16_t*)d_ws;
        const int total = NQ + NP + NB;
        prep_kernel<<<(total + 255) / 256, 256, 0, stream>>>(w_qkv, w_proj, table, wpre);
        winattn_mfma3<true><<<grid, 512, 0, stream>>>(x, mask, nW, nblocks, w_qkv, b_qkv,
                                                      w_proj, b_proj, table, wpre, out);
    } else {
        winattn_mfma3<false><<<grid, 512, 0, stream>>>(x, mask, nW, nblocks, w_qkv, b_qkv,
                                                       w_proj, b_proj, table, nullptr, out);
    }
}

// Round 2
// 459.603 us; speedup vs baseline: 1.5503x; 1.5503x over previous
//
#include <hip/hip_runtime.h>
#include <stdint.h>

#define NTOK 49
#define DIM  192
#define QKV3 576
#define NHEADS 6

typedef __attribute__((ext_vector_type(8))) short short8;
typedef __attribute__((ext_vector_type(4))) float f32x4;

__device__ __forceinline__ uint16_t f2bf(float f) {
    uint32_t u = __float_as_uint(f);
    return (uint16_t)((u + 0x7FFFu + ((u >> 16) & 1u)) >> 16);  // RNE
}
__device__ __forceinline__ uint32_t cvtpk_bf16(float a, float b) {
    uint32_t r;
    asm("v_cvt_pk_bf16_f32 %0, %1, %2" : "=v"(r) : "v"(a), "v"(b));
    return r;  // low 16 = bf16(a), high 16 = bf16(b)
}

// XOR-swizzled element offset for stride-192 bf16 tiles (16B granules).
__device__ __forceinline__ int swz(int row, int col) {
    return row * 192 + ((((col >> 3) ^ (row & 7)) << 3)) + (col & 7);
}
// V^T tile: [d][64 tokens]
__device__ __forceinline__ int vswz(int d, int tok) {
    return d * 64 + ((((tok >> 3) ^ (d & 7)) << 3)) + (tok & 7);
}

// ---------------- workspace layout ----------------
// wqkvP  : NQ bf16, fragment order [ct(36)][kk(6)][lane(64)][8]   (coalesced B-frags)
// wprojP : NP bf16, fragment order [h(6)][nt(12)][lane(64)][8]
// biasT  : NB fp32, transposed C-frag order [h][mt][nt][lane][4]  (PM==1 fallback)
// fold   : nW * NB fp32, biasT + mask[wm] folded                  (PM==2)
#define NQ (QKV3 * DIM)               // 110592
#define NP (DIM * DIM)                // 36864
#define NB (NHEADS * 4 * 4 * 64 * 4)  // 24576
#define WS_BASE ((size_t)(NQ + NP) * 2 + (size_t)NB * 4)   // 393216 B

__global__ void prep_base(const float* __restrict__ wqkv,
                          const float* __restrict__ wproj,
                          const float* __restrict__ table,
                          uint16_t* __restrict__ ws) {
    int i = blockIdx.x * 256 + threadIdx.x;
    if (i < NQ) {
        // [ct][kk][lane][jj] = wqkv[(kk*32 + (lane>>4)*8 + jj) * 576 + ct*16 + (lane&15)]
        int ct   = i / 3072;
        int rem  = i - ct * 3072;
        int kk   = rem >> 9;
        int lane = (rem >> 3) & 63;
        int jj   = rem & 7;
        int col  = ct * 16 + (lane & 15);
        int k    = kk * 32 + (lane >> 4) * 8 + jj;
        ws[i] = f2bf(wqkv[(size_t)k * QKV3 + col]);
    } else if (i < NQ + NP) {
        int j    = i - NQ;
        int hn   = j >> 9;             // h*12 + nt
        int lane = (j >> 3) & 63;
        int jj   = j & 7;
        int h    = hn / 12, nt = hn - h * 12;
        int col  = nt * 16 + (lane & 15);
        int k    = h * 32 + (lane >> 4) * 8 + jj;
        ws[NQ + j] = f2bf(wproj[(size_t)k * DIM + col]);
    } else if (i < NQ + NP + NB) {
        int e    = i - NQ - NP;
        int ii   = e & 3;
        int lane = (e >> 2) & 63;
        int nt   = (e >> 8) & 3;
        int mt   = (e >> 10) & 3;
        int h    = e >> 12;
        int r = mt * 16 + (lane & 15);               // qt
        int c = nt * 16 + ((lane >> 4) << 2) + ii;   // kt
        float val = 0.f;
        if (r < NTOK && c < NTOK) {
            int rm = r % 7, rd = r / 7, cm = c % 7, cd = c / 7;
            val = table[(13 * (rm - cm + 6) + (rd - cd + 6)) * NHEADS + h];
        }
        ((float*)(ws + NQ + NP))[e] = val;
    }
}

// fold[wm][e] = biasT[e] + mask[wm][qa][ka]  (clamped indices, matches kernel)
__global__ void prep_fold(const float* __restrict__ mask,
                          const float* __restrict__ table,
                          float* __restrict__ fold) {
    __shared__ float msk[NTOK * NTOK];
    const int wm  = blockIdx.x / (NB / 256);
    const int sub = blockIdx.x % (NB / 256);
    for (int i = threadIdx.x; i < NTOK * NTOK; i += 256)
        msk[i] = mask[(size_t)wm * (NTOK * NTOK) + i];
    __syncthreads();
    int e    = sub * 256 + threadIdx.x;
    int ii   = e & 3;
    int lane = (e >> 2) & 63;
    int nt   = (e >> 8) & 3;
    int mt   = (e >> 10) & 3;
    int h    = e >> 12;
    int r = mt * 16 + (lane & 15);
    int c = nt * 16 + ((lane >> 4) << 2) + ii;
    int qa = (r < NTOK) ? r : (NTOK - 1);
    int ka = (c < NTOK) ? c : (NTOK - 1);
    float val = msk[qa * NTOK + ka];
    if (r < NTOK && c < NTOK) {
        int rm = r % 7, rd = r / 7, cm = c % 7, cd = c / 7;
        val += table[(13 * (rm - cm + 6) + (rd - cd + 6)) * NHEADS + h];
    }
    fold[(size_t)wm * NB + e] = val;
}

// LDS element offsets (uint16 units). 81024 B -> 2 blocks/CU.
#define U_OFF   0        // x tile (49x192 swz) in phase A; per-wave pa (16x72) in phase B
#define QS_OFF  9408
#define KS_OFF  18816
#define VTA_OFF 28224    // 192x64
#define LDS_ELS 40512
#define PA_STR  72
#define R_STR   52

// ---- Phase A: register-blocked qkv GEMM. A-frags loaded once per kk;
// NCT*4 independent MFMAs per k-step; B-frags fully coalesced (PM>=1). ----
template <int NCT, int PM>
__device__ __forceinline__ void phaseA_tiles(uint16_t* lds,
                                             const uint16_t* __restrict__ wqkvP,
                                             const float* __restrict__ w_qkv,
                                             const float* __restrict__ b_qkv,
                                             const int wave, const int lane,
                                             const int q4, const int l16)
{
    const float SCALE = 0.17677669529663687f;
    f32x4 acc[NCT][4];
    #pragma unroll
    for (int j = 0; j < NCT; ++j)
        #pragma unroll
        for (int mt = 0; mt < 4; ++mt) acc[j][mt] = (f32x4){0.f, 0.f, 0.f, 0.f};

    #pragma unroll
    for (int kk = 0; kk < 6; ++kk) {
        short8 bf[NCT];
        #pragma unroll
        for (int j = 0; j < NCT; ++j) {
            const int ct = wave + 8 * j;
            if (PM >= 1) {
                bf[j] = *(const short8*)&wqkvP[(((size_t)(ct * 6 + kk)) << 9) + (lane << 3)];
            } else {
                union { uint16_t u[8]; short8 v; } tb;
                const int col = ct * 16 + l16;
                const int k0  = kk * 32 + q4 * 8;
                #pragma unroll
                for (int jj = 0; jj < 8; ++jj)
                    tb.u[jj] = f2bf(w_qkv[(size_t)(k0 + jj) * QKV3 + col]);
                bf[j] = tb.v;
            }
        }
        #pragma unroll
        for (int mt = 0; mt < 4; ++mt) {
            short8 af = *(const short8*)&lds[U_OFF + swz(mt * 16 + l16, kk * 32 + q4 * 8)];
            #pragma unroll
            for (int j = 0; j < NCT; ++j)
                acc[j][mt] = __builtin_amdgcn_mfma_f32_16x16x32_bf16(af, bf[j], acc[j][mt], 0, 0, 0);
        }
    }

    #pragma unroll
    for (int j = 0; j < NCT; ++j) {
        const int ct  = wave + 8 * j;
        const int col = ct * 16 + l16;
        const float bias = b_qkv[col];
        if (col < DIM) {                       // Q (pre-scaled)
            #pragma unroll
            for (int mt = 0; mt < 4; ++mt)
                #pragma unroll
                for (int i = 0; i < 4; ++i) {
                    int tok = mt * 16 + q4 * 4 + i;
                    if (tok < NTOK)
                        lds[QS_OFF + swz(tok, col)] = f2bf((acc[j][mt][i] + bias) * SCALE);
                }
        } else if (col < 2 * DIM) {            // K
            const int kc = col - DIM;
            #pragma unroll
            for (int mt = 0; mt < 4; ++mt)
                #pragma unroll
                for (int i = 0; i < 4; ++i) {
                    int tok = mt * 16 + q4 * 4 + i;
                    if (tok < NTOK)
                        lds[KS_OFF + swz(tok, kc)] = f2bf(acc[j][mt][i] + bias);
                }
        } else {                               // V -> transposed [d][tok], b64-packed
            const int vc = col - 2 * DIM;
            #pragma unroll
            for (int mt = 0; mt < 4; ++mt) {
                const int tokb = mt * 16 + q4 * 4;
                union { uint16_t u[4]; ushort4 v; } pv;
                #pragma unroll
                for (int i = 0; i < 4; ++i) {
                    int tok = tokb + i;
                    pv.u[i] = (tok < NTOK) ? f2bf(acc[j][mt][i] + bias) : (uint16_t)0;
                }
                *(ushort4*)&lds[VTA_OFF + vc * 64 + ((((tokb >> 3) ^ (vc & 7)) << 3)) + (tokb & 7)] = pv.v;
            }
        }
    }
}

template <int PM>
__global__ __launch_bounds__(512, 4)
void winattn_mfma4(const float* __restrict__ x,
                   const float* __restrict__ mask, int nW,
                   const float* __restrict__ w_qkv,
                   const float* __restrict__ b_qkv,
                   const float* __restrict__ w_proj,
                   const float* __restrict__ b_proj,
                   const float* __restrict__ table,
                   const uint16_t* __restrict__ wpre,
                   const float* __restrict__ fold,
                   float* __restrict__ out)
{
    __shared__ __align__(16) uint16_t lds[LDS_ELS];

    const int b    = blockIdx.x;
    const int t    = threadIdx.x;
    const int wave = t >> 6;
    const int lane = t & 63;
    const int q4   = lane >> 4;
    const int l16  = lane & 15;

    const uint16_t* wqkvP  = wpre;
    const uint16_t* wprojP = wpre + NQ;
    const float*    biasT  = (const float*)(wpre + NQ + NP);
    const float*    maskw  = mask + (size_t)(b % nW) * (NTOK * NTOK);
    const float*    foldw  = (PM == 2) ? (fold + (size_t)(b % nW) * NB) : nullptr;

    // ---------- Phase 0: x -> swizzled bf16 tile ----------
    {
        const float4* xb = (const float4*)(x + (size_t)b * (NTOK * DIM));
        for (int i = t; i < NTOK * DIM / 4; i += 512) {
            float4 v = xb[i];
            int e = i * 4, row = e / DIM, col = e - row * DIM;
            union { uint16_t u[4]; ushort4 v4; } s;
            s.u[0] = f2bf(v.x); s.u[1] = f2bf(v.y);
            s.u[2] = f2bf(v.z); s.u[3] = f2bf(v.w);
            *(ushort4*)&lds[U_OFF + swz(row, col)] = s.v4;
        }
    }
    __syncthreads();   // S1

    // ---------- Phase A ----------
    if (wave < 4) phaseA_tiles<5, PM>(lds, wqkvP, w_qkv, b_qkv, wave, lane, q4, l16);
    else          phaseA_tiles<4, PM>(lds, wqkvP, w_qkv, b_qkv, wave, lane, q4, l16);
    __syncthreads();   // S2

    // ---------- Phase B: attention (P^T softmax), zero barriers ----------
    const int mt    = wave & 3;
    const int hbase = (wave >> 2) * 3;
    uint16_t* paw = &lds[U_OFF + wave * (16 * PA_STR)];
    const int qt = mt * 16 + l16;
    const int qa = (qt < NTOK) ? qt : (NTOK - 1);

    f32x4 pacc[12];
    #pragma unroll
    for (int nt = 0; nt < 12; ++nt) pacc[nt] = (f32x4){0.f, 0.f, 0.f, 0.f};

    for (int hi = 0; hi < 3; ++hi) {
        const int h = hbase + hi;
        // --- QK^T swapped: lg[nt][i] = S[kt = nt*16+q4*4+i][qt = mt*16+l16] ---
        short8 bq = *(const short8*)&lds[QS_OFF + swz(qt, h * 32 + q4 * 8)];
        f32x4 lg[4];
        #pragma unroll
        for (int nt = 0; nt < 4; ++nt) {
            short8 ak = *(const short8*)&lds[KS_OFF + swz(nt * 16 + l16, h * 32 + q4 * 8)];
            f32x4 z = (f32x4){0.f, 0.f, 0.f, 0.f};
            lg[nt] = __builtin_amdgcn_mfma_f32_16x16x32_bf16(ak, bq, z, 0, 0, 0);
        }
        // --- + rel-pos bias + mask ---
        #pragma unroll
        for (int nt = 0; nt < 4; ++nt) {
            if (PM == 2) {
                f32x4 bb = *(const f32x4*)&foldw[(((h * 4 + mt) * 4 + nt) * 64 + lane) * 4];
                #pragma unroll
                for (int i = 0; i < 4; ++i) lg[nt][i] += bb[i];
            } else if (PM == 1) {
                f32x4 bb = *(const f32x4*)&biasT[(((h * 4 + mt) * 4 + nt) * 64 + lane) * 4];
                #pragma unroll
                for (int i = 0; i < 4; ++i) {
                    int kt = nt * 16 + q4 * 4 + i;
                    int ka = (kt < NTOK) ? kt : (NTOK - 1);
                    lg[nt][i] += bb[i] + maskw[qa * NTOK + ka];
                }
            } else {
                #pragma unroll
                for (int i = 0; i < 4; ++i) {
                    int kt = nt * 16 + q4 * 4 + i;
                    int ka = (kt < NTOK) ? kt : (NTOK - 1);
                    int rm = qa % 7, rd = qa / 7, cm = ka % 7, cd = ka / 7;
                    int bi = 13 * (rm - cm + 6) + (rd - cd + 6);
                    lg[nt][i] += table[bi * NHEADS + h] + maskw[qa * NTOK + ka];
                }
            }
        }
        // --- softmax: row lane-local over regs + 2 shfls across q4 groups ---
        float m = lg[0][0];
        #pragma unroll
        for (int nt = 0; nt < 3; ++nt)
            #pragma unroll
            for (int i = 0; i < 4; ++i) m = fmaxf(m, lg[nt][i]);
        if (q4 == 0) m = fmaxf(m, lg[3][0]);      // kt == 48 only
        m = fmaxf(m, __shfl_xor(m, 16));
        m = fmaxf(m, __shfl_xor(m, 32));
        float s = 0.f;
        #pragma unroll
        for (int nt = 0; nt < 3; ++nt)
            #pragma unroll
            for (int i = 0; i < 4; ++i) { lg[nt][i] = __expf(lg[nt][i] - m); s += lg[nt][i]; }
        float e30 = (q4 == 0) ? __expf(lg[3][0] - m) : 0.f;   // zero kt>=49: no NaN leak
        s += e30;
        s += __shfl_xor(s, 16);
        s += __shfl_xor(s, 32);
        const float inv = 1.f / s;
        // --- pack P rows -> paw[qt_local][kt], b64 writes ---
        #pragma unroll
        for (int nt = 0; nt < 3; ++nt) {
            uint32_t lo = cvtpk_bf16(lg[nt][0] * inv, lg[nt][1] * inv);
            uint32_t hi = cvtpk_bf16(lg[nt][2] * inv, lg[nt][3] * inv);
            uint32_t* dst = (uint32_t*)&paw[l16 * PA_STR + nt * 16 + q4 * 4];
            dst[0] = lo; dst[1] = hi;
        }
        {
            uint32_t lo = cvtpk_bf16(e30 * inv, 0.f);
            uint32_t* dst = (uint32_t*)&paw[l16 * PA_STR + 48 + q4 * 4];
            dst[0] = lo; dst[1] = 0u;
        }
        asm volatile("" ::: "memory");   // in-order LDS within wave

        // --- PV: out tile 16x32 ---
        f32x4 ov[2];
        ov[0] = (f32x4){0.f, 0.f, 0.f, 0.f};
        ov[1] = (f32x4){0.f, 0.f, 0.f, 0.f};
        #pragma unroll
        for (int kk = 0; kk < 2; ++kk) {
            short8 ap = *(const short8*)&paw[l16 * PA_STR + kk * 32 + q4 * 8];
            #pragma unroll
            for (int n2 = 0; n2 < 2; ++n2) {
                short8 bv = *(const short8*)&lds[VTA_OFF + vswz(h * 32 + n2 * 16 + l16,
                                                                kk * 32 + q4 * 8)];
                ov[n2] = __builtin_amdgcn_mfma_f32_16x16x32_bf16(ap, bv, ov[n2], 0, 0, 0);
            }
        }
        // --- transpose out-tile through the same private scratch ---
        asm volatile("" ::: "memory");
        #pragma unroll
        for (int n2 = 0; n2 < 2; ++n2)
            #pragma unroll
            for (int i = 0; i < 4; ++i)
                paw[(q4 * 4 + i) * PA_STR + n2 * 16 + l16] = f2bf(ov[n2][i]);
        asm volatile("" ::: "memory");

        // --- proj partial: acc += os_h(16x32) @ wproj[h-slice](32x192) ---
        short8 ap2 = *(const short8*)&paw[l16 * PA_STR + q4 * 8];
        #pragma unroll
        for (int nt = 0; nt < 12; ++nt) {
            short8 bw;
            if (PM >= 1) {
                bw = *(const short8*)&wprojP[(((size_t)(h * 12 + nt)) << 9) + (lane << 3)];
            } else {
                union { uint16_t u[8]; short8 v; } tb;
                int k0 = h * 32 + q4 * 8;
                #pragma unroll
                for (int j = 0; j < 8; ++j)
                    tb.u[j] = f2bf(w_proj[(size_t)(k0 + j) * DIM + nt * 16 + l16]);
                bw = tb.v;
            }
            pacc[nt] = __builtin_amdgcn_mfma_f32_16x16x32_bf16(ap2, bw, pacc[nt], 0, 0, 0);
        }
    }
    __syncthreads();   // S3: all tasks done; qs/ks/vta/pa dead

    // ---------- Phase C: cross-wave-pair reduction + writeout ----------
    float* R = (float*)lds;
    if (wave >= 4) {
        float* rw = R + (size_t)(mt * 64 + lane) * R_STR;
        #pragma unroll
        for (int nt = 0; nt < 12; ++nt)
            *(f32x4*)(rw + nt * 4) = pacc[nt];
    }
    __syncthreads();   // S4
    if (wave < 4) {
        const float* rr = R + (size_t)(mt * 64 + lane) * R_STR;
        float* ob = out + (size_t)b * (NTOK * DIM);
        #pragma unroll
        for (int nt = 0; nt < 12; ++nt) {
            f32x4 other = *(const f32x4*)(rr + nt * 4);
            const int c = nt * 16 + l16;
            const float bp = b_proj[c];
            #pragma unroll
            for (int i = 0; i < 4; ++i) {
                const int r = mt * 16 + q4 * 4 + i;
                if (r < NTOK) ob[r * DIM + c] = pacc[nt][i] + other[i] + bp;
            }
        }
    }
}

extern "C" void kernel_launch(void* const* d_in, const int* in_sizes, int n_in,
                              void* d_out, int out_size, void* d_ws, size_t ws_size,
                              hipStream_t stream) {
    const float* x      = (const float*)d_in[0];
    const float* mask   = (const float*)d_in[1];
    const float* w_qkv  = (const float*)d_in[2];
    const float* b_qkv  = (const float*)d_in[3];
    const float* w_proj = (const float*)d_in[4];
    const float* b_proj = (const float*)d_in[5];
    const float* table  = (const float*)d_in[6];
    float* out = (float*)d_out;

    const int nblocks = in_sizes[0] / (NTOK * DIM);   // 4096 windows
    const int nW      = in_sizes[1] / (NTOK * NTOK);  // 64
    const size_t WS_FOLD = (size_t)nW * NB * 4;       // 6291456 for nW=64

    if (d_ws != nullptr && ws_size >= WS_BASE + WS_FOLD) {
        uint16_t* wpre = (uint16_t*)d_ws;
        float* fold = (float*)((char*)d_ws + WS_BASE);
        const int total = NQ + NP + NB;
        prep_base<<<(total + 255) / 256, 256, 0, stream>>>(w_qkv, w_proj, table, wpre);
        prep_fold<<<nW * (NB / 256), 256, 0, stream>>>(mask, table, fold);
        winattn_mfma4<2><<<nblocks, 512, 0, stream>>>(x, mask, nW, w_qkv, b_qkv,
                                                      w_proj, b_proj, table, wpre, fold, out);
    } else if (d_ws != nullptr && ws_size >= WS_BASE) {
        uint16_t* wpre = (uint16_t*)d_ws;
        const int total = NQ + NP + NB;
        prep_base<<<(total + 255) / 256, 256, 0, stream>>>(w_qkv, w_proj, table, wpre);
        winattn_mfma4<1><<<nblocks, 512, 0, stream>>>(x, mask, nW, w_qkv, b_qkv,
                                                      w_proj, b_proj, table, wpre, nullptr, out);
    } else {
        winattn_mfma4<0><<<nblocks, 512, 0, stream>>>(x, mask, nW, w_qkv, b_qkv,
                                                      w_proj, b_proj, table, nullptr, nullptr, out);
    }
}

// Round 3
// 441.534 us; speedup vs baseline: 1.6138x; 1.0409x over previous
//
#include <hip/hip_runtime.h>
#include <stdint.h>

#define NTOK 49
#define DIM  192
#define QKV3 576
#define NHEADS 6

typedef __attribute__((ext_vector_type(8))) short short8;
typedef __attribute__((ext_vector_type(4))) float f32x4;

__device__ __forceinline__ uint16_t f2bf(float f) {
    uint32_t u = __float_as_uint(f);
    return (uint16_t)((u + 0x7FFFu + ((u >> 16) & 1u)) >> 16);  // RNE
}
__device__ __forceinline__ uint32_t cvtpk_bf16(float a, float b) {
    uint32_t r;
    asm("v_cvt_pk_bf16_f32 %0, %1, %2" : "=v"(r) : "v"(a), "v"(b));
    return r;  // low 16 = bf16(a), high 16 = bf16(b)
}

// XOR-swizzled element offset for stride-192 bf16 tiles (16B granules).
__device__ __forceinline__ int swz(int row, int col) {
    return row * 192 + ((((col >> 3) ^ (row & 7)) << 3)) + (col & 7);
}
// V^T tile: [d][64 tokens]
__device__ __forceinline__ int vswz(int d, int tok) {
    return d * 64 + ((((tok >> 3) ^ (d & 7)) << 3)) + (tok & 7);
}

// ---------------- workspace layout ----------------
// wqkvP  : NQ bf16, fragment order [ct(36)][kk(6)][lane(64)][8]   (coalesced B-frags)
// wprojP : NP bf16, fragment order [h(6)][nt(12)][lane(64)][8]
// biasT  : NB fp32, transposed C-frag order [h][mt][nt][lane][4]  (PM==1 fallback)
// fold   : nW * NB fp32, biasT + mask[wm] folded                  (PM==2)
#define NQ (QKV3 * DIM)               // 110592
#define NP (DIM * DIM)                // 36864
#define NB (NHEADS * 4 * 4 * 64 * 4)  // 24576
#define WS_BASE ((size_t)(NQ + NP) * 2 + (size_t)NB * 4)   // 393216 B

__global__ void prep_base(const float* __restrict__ wqkv,
                          const float* __restrict__ wproj,
                          const float* __restrict__ table,
                          uint16_t* __restrict__ ws) {
    int i = blockIdx.x * 256 + threadIdx.x;
    if (i < NQ) {
        // [ct][kk][lane][jj] = wqkv[(kk*32 + (lane>>4)*8 + jj) * 576 + ct*16 + (lane&15)]
        int ct   = i / 3072;
        int rem  = i - ct * 3072;
        int kk   = rem >> 9;
        int lane = (rem >> 3) & 63;
        int jj   = rem & 7;
        int col  = ct * 16 + (lane & 15);
        int k    = kk * 32 + (lane >> 4) * 8 + jj;
        ws[i] = f2bf(wqkv[(size_t)k * QKV3 + col]);
    } else if (i < NQ + NP) {
        int j    = i - NQ;
        int hn   = j >> 9;             // h*12 + nt
        int lane = (j >> 3) & 63;
        int jj   = j & 7;
        int h    = hn / 12, nt = hn - h * 12;
        int col  = nt * 16 + (lane & 15);
        int k    = h * 32 + (lane >> 4) * 8 + jj;
        ws[NQ + j] = f2bf(wproj[(size_t)k * DIM + col]);
    } else if (i < NQ + NP + NB) {
        int e    = i - NQ - NP;
        int ii   = e & 3;
        int lane = (e >> 2) & 63;
        int nt   = (e >> 8) & 3;
        int mt   = (e >> 10) & 3;
        int h    = e >> 12;
        int r = mt * 16 + (lane & 15);               // qt
        int c = nt * 16 + ((lane >> 4) << 2) + ii;   // kt
        float val = 0.f;
        if (r < NTOK && c < NTOK) {
            int rm = r % 7, rd = r / 7, cm = c % 7, cd = c / 7;
            val = table[(13 * (rm - cm + 6) + (rd - cd + 6)) * NHEADS + h];
        }
        ((float*)(ws + NQ + NP))[e] = val;
    }
}

// fold[wm][e] = biasT[e] + mask[wm][qa][ka]  (clamped indices, matches kernel)
__global__ void prep_fold(const float* __restrict__ mask,
                          const float* __restrict__ table,
                          float* __restrict__ fold) {
    __shared__ float msk[NTOK * NTOK];
    const int wm  = blockIdx.x / (NB / 256);
    const int sub = blockIdx.x % (NB / 256);
    for (int i = threadIdx.x; i < NTOK * NTOK; i += 256)
        msk[i] = mask[(size_t)wm * (NTOK * NTOK) + i];
    __syncthreads();
    int e    = sub * 256 + threadIdx.x;
    int ii   = e & 3;
    int lane = (e >> 2) & 63;
    int nt   = (e >> 8) & 3;
    int mt   = (e >> 10) & 3;
    int h    = e >> 12;
    int r = mt * 16 + (lane & 15);
    int c = nt * 16 + ((lane >> 4) << 2) + ii;
    int qa = (r < NTOK) ? r : (NTOK - 1);
    int ka = (c < NTOK) ? c : (NTOK - 1);
    float val = msk[qa * NTOK + ka];
    if (r < NTOK && c < NTOK) {
        int rm = r % 7, rd = r / 7, cm = c % 7, cd = c / 7;
        val += table[(13 * (rm - cm + 6) + (rd - cd + 6)) * NHEADS + h];
    }
    fold[(size_t)wm * NB + e] = val;
}

// LDS element offsets (uint16 units). 81024 B -> 2 blocks/CU.
#define U_OFF   0        // x tile (49x192 swz) in phase A; per-wave pa (16x72) in phase B
#define QS_OFF  9408
#define KS_OFF  18816
#define VTA_OFF 28224    // 192x64
#define LDS_ELS 40512
#define PA_STR  72
#define R_STR   52

// ---- Phase A pass: NCT col-tiles (ct = base + 8*j). acc scoped per call so
// accumulator liveness stays at NCT*16 AGPRs (<=64) -> no scratch spill. ----
template <int NCT, int PM>
__device__ __forceinline__ void phaseA_pass(uint16_t* lds,
                                            const uint16_t* __restrict__ wqkvP,
                                            const float* __restrict__ w_qkv,
                                            const float* __restrict__ b_qkv,
                                            const int base, const int lane,
                                            const int q4, const int l16)
{
    const float SCALE = 0.17677669529663687f;
    f32x4 acc[NCT][4];
    #pragma unroll
    for (int j = 0; j < NCT; ++j)
        #pragma unroll
        for (int mt = 0; mt < 4; ++mt) acc[j][mt] = (f32x4){0.f, 0.f, 0.f, 0.f};

    #pragma unroll
    for (int kk = 0; kk < 6; ++kk) {
        short8 bf[NCT];
        #pragma unroll
        for (int j = 0; j < NCT; ++j) {
            const int ct = base + 8 * j;
            if (PM >= 1) {
                bf[j] = *(const short8*)&wqkvP[(((size_t)(ct * 6 + kk)) << 9) + (lane << 3)];
            } else {
                union { uint16_t u[8]; short8 v; } tb;
                const int col = ct * 16 + l16;
                const int k0  = kk * 32 + q4 * 8;
                #pragma unroll
                for (int jj = 0; jj < 8; ++jj)
                    tb.u[jj] = f2bf(w_qkv[(size_t)(k0 + jj) * QKV3 + col]);
                bf[j] = tb.v;
            }
        }
        #pragma unroll
        for (int mt = 0; mt < 4; ++mt) {
            short8 af = *(const short8*)&lds[U_OFF + swz(mt * 16 + l16, kk * 32 + q4 * 8)];
            #pragma unroll
            for (int j = 0; j < NCT; ++j)
                acc[j][mt] = __builtin_amdgcn_mfma_f32_16x16x32_bf16(af, bf[j], acc[j][mt], 0, 0, 0);
        }
    }

    #pragma unroll
    for (int j = 0; j < NCT; ++j) {
        const int ct  = base + 8 * j;
        const int col = ct * 16 + l16;
        const float bias = b_qkv[col];
        if (col < DIM) {                       // Q (pre-scaled)
            #pragma unroll
            for (int mt = 0; mt < 4; ++mt)
                #pragma unroll
                for (int i = 0; i < 4; ++i) {
                    int tok = mt * 16 + q4 * 4 + i;
                    if (tok < NTOK)
                        lds[QS_OFF + swz(tok, col)] = f2bf((acc[j][mt][i] + bias) * SCALE);
                }
        } else if (col < 2 * DIM) {            // K
            const int kc = col - DIM;
            #pragma unroll
            for (int mt = 0; mt < 4; ++mt)
                #pragma unroll
                for (int i = 0; i < 4; ++i) {
                    int tok = mt * 16 + q4 * 4 + i;
                    if (tok < NTOK)
                        lds[KS_OFF + swz(tok, kc)] = f2bf(acc[j][mt][i] + bias);
                }
        } else {                               // V -> transposed [d][tok], b64-packed
            const int vc = col - 2 * DIM;
            #pragma unroll
            for (int mt = 0; mt < 4; ++mt) {
                const int tokb = mt * 16 + q4 * 4;
                union { uint16_t u[4]; ushort4 v; } pv;
                #pragma unroll
                for (int i = 0; i < 4; ++i) {
                    int tok = tokb + i;
                    pv.u[i] = (tok < NTOK) ? f2bf(acc[j][mt][i] + bias) : (uint16_t)0;
                }
                *(ushort4*)&lds[VTA_OFF + vc * 64 + ((((tokb >> 3) ^ (vc & 7)) << 3)) + (tokb & 7)] = pv.v;
            }
        }
    }
}

template <int PM>
__global__ __launch_bounds__(512, 4)
void winattn_mfma5(const float* __restrict__ x,
                   const float* __restrict__ mask, int nW,
                   const float* __restrict__ w_qkv,
                   const float* __restrict__ b_qkv,
                   const float* __restrict__ w_proj,
                   const float* __restrict__ b_proj,
                   const float* __restrict__ table,
                   const uint16_t* __restrict__ wpre,
                   const float* __restrict__ fold,
                   float* __restrict__ out)
{
    __shared__ __align__(16) uint16_t lds[LDS_ELS];

    const int b    = blockIdx.x;
    const int t    = threadIdx.x;
    const int wave = t >> 6;
    const int lane = t & 63;
    const int q4   = lane >> 4;
    const int l16  = lane & 15;

    const uint16_t* wqkvP  = wpre;
    const uint16_t* wprojP = wpre + NQ;
    const float*    biasT  = (const float*)(wpre + NQ + NP);
    const float*    maskw  = mask + (size_t)(b % nW) * (NTOK * NTOK);
    const float*    foldw  = (PM == 2) ? (fold + (size_t)(b % nW) * NB) : nullptr;

    // ---------- Phase 0: x -> swizzled bf16 tile ----------
    {
        const float4* xb = (const float4*)(x + (size_t)b * (NTOK * DIM));
        for (int i = t; i < NTOK * DIM / 4; i += 512) {
            float4 v = xb[i];
            int e = i * 4, row = e / DIM, col = e - row * DIM;
            union { uint16_t u[4]; ushort4 v4; } s;
            s.u[0] = f2bf(v.x); s.u[1] = f2bf(v.y);
            s.u[2] = f2bf(v.z); s.u[3] = f2bf(v.w);
            *(ushort4*)&lds[U_OFF + swz(row, col)] = s.v4;
        }
    }
    __syncthreads();   // S1

    // ---------- Phase A: pass1 tiles 0..31 (NCT=4), pass2 tiles 32..35 ----------
    phaseA_pass<4, PM>(lds, wqkvP, w_qkv, b_qkv, wave, lane, q4, l16);
    if (wave < 4)
        phaseA_pass<1, PM>(lds, wqkvP, w_qkv, b_qkv, 32 + wave, lane, q4, l16);
    __syncthreads();   // S2

    // ---------- Phase B: attention (P^T softmax), zero barriers ----------
    const int mt    = wave & 3;
    const int hbase = (wave >> 2) * 3;
    uint16_t* paw = &lds[U_OFF + wave * (16 * PA_STR)];
    const int qt = mt * 16 + l16;
    const int qa = (qt < NTOK) ? qt : (NTOK - 1);

    f32x4 pacc[12];
    #pragma unroll
    for (int nt = 0; nt < 12; ++nt) pacc[nt] = (f32x4){0.f, 0.f, 0.f, 0.f};

    for (int hi = 0; hi < 3; ++hi) {
        const int h = hbase + hi;
        // --- QK^T swapped: lg[nt][i] = S[kt = nt*16+q4*4+i][qt = mt*16+l16] ---
        short8 bq = *(const short8*)&lds[QS_OFF + swz(qt, h * 32 + q4 * 8)];
        f32x4 lg[4];
        __builtin_amdgcn_s_setprio(1);
        #pragma unroll
        for (int nt = 0; nt < 4; ++nt) {
            short8 ak = *(const short8*)&lds[KS_OFF + swz(nt * 16 + l16, h * 32 + q4 * 8)];
            f32x4 z = (f32x4){0.f, 0.f, 0.f, 0.f};
            lg[nt] = __builtin_amdgcn_mfma_f32_16x16x32_bf16(ak, bq, z, 0, 0, 0);
        }
        __builtin_amdgcn_s_setprio(0);
        // --- + rel-pos bias + mask ---
        #pragma unroll
        for (int nt = 0; nt < 4; ++nt) {
            if (PM == 2) {
                f32x4 bb = *(const f32x4*)&foldw[(((h * 4 + mt) * 4 + nt) * 64 + lane) * 4];
                #pragma unroll
                for (int i = 0; i < 4; ++i) lg[nt][i] += bb[i];
            } else if (PM == 1) {
                f32x4 bb = *(const f32x4*)&biasT[(((h * 4 + mt) * 4 + nt) * 64 + lane) * 4];
                #pragma unroll
                for (int i = 0; i < 4; ++i) {
                    int kt = nt * 16 + q4 * 4 + i;
                    int ka = (kt < NTOK) ? kt : (NTOK - 1);
                    lg[nt][i] += bb[i] + maskw[qa * NTOK + ka];
                }
            } else {
                #pragma unroll
                for (int i = 0; i < 4; ++i) {
                    int kt = nt * 16 + q4 * 4 + i;
                    int ka = (kt < NTOK) ? kt : (NTOK - 1);
                    int rm = qa % 7, rd = qa / 7, cm = ka % 7, cd = ka / 7;
                    int bi = 13 * (rm - cm + 6) + (rd - cd + 6);
                    lg[nt][i] += table[bi * NHEADS + h] + maskw[qa * NTOK + ka];
                }
            }
        }
        // --- softmax: row lane-local over regs + 2 shfls across q4 groups ---
        float m = lg[0][0];
        #pragma unroll
        for (int nt = 0; nt < 3; ++nt)
            #pragma unroll
            for (int i = 0; i < 4; ++i) m = fmaxf(m, lg[nt][i]);
        if (q4 == 0) m = fmaxf(m, lg[3][0]);      // kt == 48 only
        m = fmaxf(m, __shfl_xor(m, 16));
        m = fmaxf(m, __shfl_xor(m, 32));
        float s = 0.f;
        #pragma unroll
        for (int nt = 0; nt < 3; ++nt)
            #pragma unroll
            for (int i = 0; i < 4; ++i) { lg[nt][i] = __expf(lg[nt][i] - m); s += lg[nt][i]; }
        float e30 = (q4 == 0) ? __expf(lg[3][0] - m) : 0.f;   // zero kt>=49: no NaN leak
        s += e30;
        s += __shfl_xor(s, 16);
        s += __shfl_xor(s, 32);
        const float inv = 1.f / s;
        // --- pack P rows -> paw[qt_local][kt], b64 writes ---
        #pragma unroll
        for (int nt = 0; nt < 3; ++nt) {
            uint32_t lo = cvtpk_bf16(lg[nt][0] * inv, lg[nt][1] * inv);
            uint32_t hi = cvtpk_bf16(lg[nt][2] * inv, lg[nt][3] * inv);
            uint32_t* dst = (uint32_t*)&paw[l16 * PA_STR + nt * 16 + q4 * 4];
            dst[0] = lo; dst[1] = hi;
        }
        {
            uint32_t lo = cvtpk_bf16(e30 * inv, 0.f);
            uint32_t* dst = (uint32_t*)&paw[l16 * PA_STR + 48 + q4 * 4];
            dst[0] = lo; dst[1] = 0u;
        }
        asm volatile("" ::: "memory");   // in-order LDS within wave

        // --- PV: out tile 16x32 ---
        f32x4 ov[2];
        ov[0] = (f32x4){0.f, 0.f, 0.f, 0.f};
        ov[1] = (f32x4){0.f, 0.f, 0.f, 0.f};
        __builtin_amdgcn_s_setprio(1);
        #pragma unroll
        for (int kk = 0; kk < 2; ++kk) {
            short8 ap = *(const short8*)&paw[l16 * PA_STR + kk * 32 + q4 * 8];
            #pragma unroll
            for (int n2 = 0; n2 < 2; ++n2) {
                short8 bv = *(const short8*)&lds[VTA_OFF + vswz(h * 32 + n2 * 16 + l16,
                                                                kk * 32 + q4 * 8)];
                ov[n2] = __builtin_amdgcn_mfma_f32_16x16x32_bf16(ap, bv, ov[n2], 0, 0, 0);
            }
        }
        __builtin_amdgcn_s_setprio(0);
        // --- transpose out-tile through the same private scratch ---
        asm volatile("" ::: "memory");
        #pragma unroll
        for (int n2 = 0; n2 < 2; ++n2)
            #pragma unroll
            for (int i = 0; i < 4; ++i)
                paw[(q4 * 4 + i) * PA_STR + n2 * 16 + l16] = f2bf(ov[n2][i]);
        asm volatile("" ::: "memory");

        // --- proj partial: acc += os_h(16x32) @ wproj[h-slice](32x192) ---
        short8 ap2 = *(const short8*)&paw[l16 * PA_STR + q4 * 8];
        __builtin_amdgcn_s_setprio(1);
        #pragma unroll
        for (int nt = 0; nt < 12; ++nt) {
            short8 bw;
            if (PM >= 1) {
                bw = *(const short8*)&wprojP[(((size_t)(h * 12 + nt)) << 9) + (lane << 3)];
            } else {
                union { uint16_t u[8]; short8 v; } tb;
                int k0 = h * 32 + q4 * 8;
                #pragma unroll
                for (int j = 0; j < 8; ++j)
                    tb.u[j] = f2bf(w_proj[(size_t)(k0 + j) * DIM + nt * 16 + l16]);
                bw = tb.v;
            }
            pacc[nt] = __builtin_amdgcn_mfma_f32_16x16x32_bf16(ap2, bw, pacc[nt], 0, 0, 0);
        }
        __builtin_amdgcn_s_setprio(0);
    }
    __syncthreads();   // S3: all tasks done; qs/ks/vta/pa dead

    // ---------- Phase C: cross-wave-pair reduction + writeout ----------
    float* R = (float*)lds;
    if (wave >= 4) {
        float* rw = R + (size_t)(mt * 64 + lane) * R_STR;
        #pragma unroll
        for (int nt = 0; nt < 12; ++nt)
            *(f32x4*)(rw + nt * 4) = pacc[nt];
    }
    __syncthreads();   // S4
    if (wave < 4) {
        const float* rr = R + (size_t)(mt * 64 + lane) * R_STR;
        float* ob = out + (size_t)b * (NTOK * DIM);
        #pragma unroll
        for (int nt = 0; nt < 12; ++nt) {
            f32x4 other = *(const f32x4*)(rr + nt * 4);
            const int c = nt * 16 + l16;
            const float bp = b_proj[c];
            #pragma unroll
            for (int i = 0; i < 4; ++i) {
                const int r = mt * 16 + q4 * 4 + i;
                if (r < NTOK) ob[r * DIM + c] = pacc[nt][i] + other[i] + bp;
            }
        }
    }
}

extern "C" void kernel_launch(void* const* d_in, const int* in_sizes, int n_in,
                              void* d_out, int out_size, void* d_ws, size_t ws_size,
                              hipStream_t stream) {
    const float* x      = (const float*)d_in[0];
    const float* mask   = (const float*)d_in[1];
    const float* w_qkv  = (const float*)d_in[2];
    const float* b_qkv  = (const float*)d_in[3];
    const float* w_proj = (const float*)d_in[4];
    const float* b_proj = (const float*)d_in[5];
    const float* table  = (const float*)d_in[6];
    float* out = (float*)d_out;

    const int nblocks = in_sizes[0] / (NTOK * DIM);   // 4096 windows
    const int nW      = in_sizes[1] / (NTOK * NTOK);  // 64
    const size_t WS_FOLD = (size_t)nW * NB * 4;       // 6291456 for nW=64

    if (d_ws != nullptr && ws_size >= WS_BASE + WS_FOLD) {
        uint16_t* wpre = (uint16_t*)d_ws;
        float* fold = (float*)((char*)d_ws + WS_BASE);
        const int total = NQ + NP + NB;
        prep_base<<<(total + 255) / 256, 256, 0, stream>>>(w_qkv, w_proj, table, wpre);
        prep_fold<<<nW * (NB / 256), 256, 0, stream>>>(mask, table, fold);
        winattn_mfma5<2><<<nblocks, 512, 0, stream>>>(x, mask, nW, w_qkv, b_qkv,
                                                      w_proj, b_proj, table, wpre, fold, out);
    } else if (d_ws != nullptr && ws_size >= WS_BASE) {
        uint16_t* wpre = (uint16_t*)d_ws;
        const int total = NQ + NP + NB;
        prep_base<<<(total + 255) / 256, 256, 0, stream>>>(w_qkv, w_proj, table, wpre);
        winattn_mfma5<1><<<nblocks, 512, 0, stream>>>(x, mask, nW, w_qkv, b_qkv,
                                                      w_proj, b_proj, table, wpre, nullptr, out);
    } else {
        winattn_mfma5<0><<<nblocks, 512, 0, stream>>>(x, mask, nW, w_qkv, b_qkv,
                                                      w_proj, b_proj, table, nullptr, nullptr, out);
    }
}

// Round 4
// 412.997 us; speedup vs baseline: 1.7253x; 1.0691x over previous
//
#include <hip/hip_runtime.h>
#include <stdint.h>

#define NTOK 49
#define DIM  192
#define QKV3 576
#define NHEADS 6
#define SCALE_F 0.17677669529663687f

typedef __attribute__((ext_vector_type(8))) short short8;
typedef __attribute__((ext_vector_type(4))) float f32x4;

__device__ __forceinline__ uint16_t f2bf(float f) {
    uint32_t u = __float_as_uint(f);
    return (uint16_t)((u + 0x7FFFu + ((u >> 16) & 1u)) >> 16);  // RNE
}
__device__ __forceinline__ uint32_t cvtpk_bf16(float a, float b) {
    uint32_t r;
    asm("v_cvt_pk_bf16_f32 %0, %1, %2" : "=v"(r) : "v"(a), "v"(b));
    return r;  // low 16 = bf16(a), high 16 = bf16(b)
}

// XOR-swizzled element offset for stride-192 bf16 tiles (16B granules).
__device__ __forceinline__ int swz(int row, int col) {
    return row * 192 + ((((col >> 3) ^ (row & 7)) << 3)) + (col & 7);
}
// V^T tile: [d][64 tokens]
__device__ __forceinline__ int vswz(int d, int tok) {
    return d * 64 + ((((tok >> 3) ^ (d & 7)) << 3)) + (tok & 7);
}

// ---------------- workspace layout (bytes) ----------------
// wqkvP  @0        : NQ bf16  [ct(36)][kk(6)][lane(64)][8]  coalesced B/A-frags
// wprojP @NQ*2     : NP bf16  [h(6)][nt(12)][lane(64)][8]
// biasT  @+NP*2    : NB f32   [h][mt][nt][lane][4] transposed C-frag rel-pos bias
// bqkvF  @OFF_BQ   : 576 f32  qkv bias, Q part prescaled by SCALE
// maskF  @OFF_MF   : nW*4096 f32 [wm][mt][nt][lane][4] mask in C-frag order
#define NQ (QKV3 * DIM)               // 110592
#define NP (DIM * DIM)                // 36864
#define NB (NHEADS * 4 * 4 * 64 * 4)  // 24576
#define OFF_BQ ((size_t)(NQ + NP) * 2 + (size_t)NB * 4)   // 393216
#define OFF_MF (OFF_BQ + 576 * 4)                         // 395520

__global__ void prep_all(const float* __restrict__ wqkv,
                         const float* __restrict__ wproj,
                         const float* __restrict__ table,
                         const float* __restrict__ bqkv,
                         const float* __restrict__ mask,
                         int nmaskels,
                         uint8_t* __restrict__ wsb) {
    uint16_t* wq = (uint16_t*)wsb;
    uint16_t* wp = (uint16_t*)(wsb + (size_t)NQ * 2);
    float*    bT = (float*)(wsb + (size_t)(NQ + NP) * 2);
    float*    bq = (float*)(wsb + OFF_BQ);
    float*    mF = (float*)(wsb + OFF_MF);
    int i = blockIdx.x * 256 + threadIdx.x;
    if (i < NQ) {
        int ct   = i / 3072;
        int rem  = i - ct * 3072;
        int kk   = rem >> 9;
        int lane = (rem >> 3) & 63;
        int jj   = rem & 7;
        int col  = ct * 16 + (lane & 15);
        int k    = kk * 32 + (lane >> 4) * 8 + jj;
        wq[i] = f2bf(wqkv[(size_t)k * QKV3 + col]);
    } else if (i < NQ + NP) {
        int j    = i - NQ;
        int hn   = j >> 9;             // h*12 + nt
        int lane = (j >> 3) & 63;
        int jj   = j & 7;
        int h    = hn / 12, nt = hn - h * 12;
        int col  = nt * 16 + (lane & 15);
        int k    = h * 32 + (lane >> 4) * 8 + jj;
        wp[j] = f2bf(wproj[(size_t)k * DIM + col]);
    } else if (i < NQ + NP + NB) {
        int e    = i - NQ - NP;
        int ii   = e & 3;
        int lane = (e >> 2) & 63;
        int nt   = (e >> 8) & 3;
        int mt   = (e >> 10) & 3;
        int h    = e >> 12;
        int r = mt * 16 + (lane & 15);               // qt
        int c = nt * 16 + ((lane >> 4) << 2) + ii;   // kt
        float val = 0.f;
        if (r < NTOK && c < NTOK) {
            int rm = r % 7, rd = r / 7, cm = c % 7, cd = c / 7;
            val = table[(13 * (rm - cm + 6) + (rd - cd + 6)) * NHEADS + h];
        }
        bT[e] = val;
    } else if (i < NQ + NP + NB + 576) {
        int e = i - NQ - NP - NB;
        bq[e] = (e < DIM) ? bqkv[e] * SCALE_F : bqkv[e];
    } else if (i < NQ + NP + NB + 576 + nmaskels) {
        int e    = i - NQ - NP - NB - 576;
        int ii   = e & 3;
        int lane = (e >> 2) & 63;
        int nt   = (e >> 8) & 3;
        int mt   = (e >> 10) & 3;
        int wm   = e >> 12;
        int r = mt * 16 + (lane & 15);
        int c = nt * 16 + ((lane >> 4) << 2) + ii;
        int qa = (r < NTOK) ? r : (NTOK - 1);
        int ka = (c < NTOK) ? c : (NTOK - 1);
        mF[e] = mask[(size_t)wm * (NTOK * NTOK) + qa * NTOK + ka];
    }
}

// LDS element offsets (uint16 units). 81024 B -> 2 blocks/CU.
#define U_OFF   0        // x tile (49x192 swz) in phase A; per-wave pa (16x72) in phase B
#define QS_OFF  9408
#define KS_OFF  18816
#define VTA_OFF 28224    // 192x64
#define LDS_ELS 40512
#define PA_STR  72
#define R_STR   52

// ---- Phase A typed pass. TGT: 0=Q, 1=K (C^T orientation, b64 row writes),
// 2=V (original orientation, b64 V^T writes). NCT<=2 so worst-case register
// liveness (all bf loads hoisted + acc) stays under the 128-reg cap. ----
template <int NCT, int TGT, int PM>
__device__ __forceinline__ void phaseA_typed(uint16_t* lds,
                                             const uint16_t* __restrict__ wqkvP,
                                             const float* __restrict__ w_qkv,
                                             const float* __restrict__ bqkvF,
                                             const float* __restrict__ b_qkv,
                                             const int ct0, const int lane,
                                             const int q4, const int l16)
{
    f32x4 acc[NCT][4];
    #pragma unroll
    for (int j = 0; j < NCT; ++j)
        #pragma unroll
        for (int tt = 0; tt < 4; ++tt) acc[j][tt] = (f32x4){0.f, 0.f, 0.f, 0.f};

    #pragma unroll
    for (int kk = 0; kk < 6; ++kk) {
        short8 bf[NCT];
        #pragma unroll
        for (int j = 0; j < NCT; ++j) {
            const int ct = ct0 + 8 * j;
            if (PM >= 1) {
                bf[j] = *(const short8*)&wqkvP[(((size_t)(ct * 6 + kk)) << 9) + (lane << 3)];
            } else {
                union { uint16_t u[8]; short8 v; } tb;
                const int col = ct * 16 + l16;
                const int k0  = kk * 32 + q4 * 8;
                #pragma unroll
                for (int jj = 0; jj < 8; ++jj)
                    tb.u[jj] = f2bf(w_qkv[(size_t)(k0 + jj) * QKV3 + col]);
                bf[j] = tb.v;
            }
        }
        #pragma unroll
        for (int tt = 0; tt < 4; ++tt) {
            short8 af = *(const short8*)&lds[U_OFF + swz(tt * 16 + l16, kk * 32 + q4 * 8)];
            #pragma unroll
            for (int j = 0; j < NCT; ++j) {
                if (TGT <= 1)   // C^T: rows=out-col, cols=token
                    acc[j][tt] = __builtin_amdgcn_mfma_f32_16x16x32_bf16(bf[j], af, acc[j][tt], 0, 0, 0);
                else            // V: rows=token, cols=out-col
                    acc[j][tt] = __builtin_amdgcn_mfma_f32_16x16x32_bf16(af, bf[j], acc[j][tt], 0, 0, 0);
            }
        }
    }

    #pragma unroll
    for (int j = 0; j < NCT; ++j) {
        const int ct = ct0 + 8 * j;
        if (TGT <= 1) {
            const int colb = ct * 16 + q4 * 4;        // global qkv col of acc[.][0]
            f32x4 b4;
            if (PM >= 1) {
                b4 = *(const f32x4*)&bqkvF[colb];     // Q part prescaled
            } else {
                #pragma unroll
                for (int i = 0; i < 4; ++i)
                    b4[i] = (TGT == 0) ? b_qkv[colb + i] * SCALE_F : b_qkv[colb + i];
            }
            const int lc   = (TGT == 0) ? colb : (colb - DIM);
            const int base = (TGT == 0) ? QS_OFF : KS_OFF;
            #pragma unroll
            for (int tt = 0; tt < 4; ++tt) {
                const int tok = tt * 16 + l16;        // lane-fixed token row
                float v0, v1, v2, v3;
                if (TGT == 0) {
                    v0 = fmaf(acc[j][tt][0], SCALE_F, b4[0]);
                    v1 = fmaf(acc[j][tt][1], SCALE_F, b4[1]);
                    v2 = fmaf(acc[j][tt][2], SCALE_F, b4[2]);
                    v3 = fmaf(acc[j][tt][3], SCALE_F, b4[3]);
                } else {
                    v0 = acc[j][tt][0] + b4[0];
                    v1 = acc[j][tt][1] + b4[1];
                    v2 = acc[j][tt][2] + b4[2];
                    v3 = acc[j][tt][3] + b4[3];
                }
                uint2 pw;
                pw.x = cvtpk_bf16(v0, v1);
                pw.y = cvtpk_bf16(v2, v3);
                if (tok < NTOK)
                    *(uint2*)&lds[base + swz(tok, lc)] = pw;   // 4 cols, one b64
            }
        } else {
            const int col = ct * 16 + l16;            // 384..575
            const int vc  = col - 2 * DIM;
            const float bias = (PM >= 1) ? bqkvF[col] : b_qkv[col];
            #pragma unroll
            for (int mt = 0; mt < 4; ++mt) {
                const int tokb = mt * 16 + q4 * 4;
                float z0 = (tokb + 0 < NTOK) ? acc[j][mt][0] + bias : 0.f;
                float z1 = (tokb + 1 < NTOK) ? acc[j][mt][1] + bias : 0.f;
                float z2 = (tokb + 2 < NTOK) ? acc[j][mt][2] + bias : 0.f;
                float z3 = (tokb + 3 < NTOK) ? acc[j][mt][3] + bias : 0.f;
                uint2 pw;
                pw.x = cvtpk_bf16(z0, z1);
                pw.y = cvtpk_bf16(z2, z3);
                *(uint2*)&lds[VTA_OFF + vc * 64 +
                              ((((tokb >> 3) ^ (vc & 7)) << 3)) + (tokb & 7)] = pw;
            }
        }
    }
}

template <int PM>
__global__ __launch_bounds__(512, 4)
void winattn_mfma6(const float* __restrict__ x,
                   const float* __restrict__ mask, int nW,
                   const float* __restrict__ w_qkv,
                   const float* __restrict__ b_qkv,
                   const float* __restrict__ w_proj,
                   const float* __restrict__ b_proj,
                   const float* __restrict__ table,
                   const uint8_t* __restrict__ wsb,
                   float* __restrict__ out)
{
    __shared__ __align__(16) uint16_t lds[LDS_ELS];

    const int b    = blockIdx.x;
    const int t    = threadIdx.x;
    const int wave = t >> 6;
    const int lane = t & 63;
    const int q4   = lane >> 4;
    const int l16  = lane & 15;

    const uint16_t* wqkvP  = (const uint16_t*)wsb;
    const uint16_t* wprojP = (const uint16_t*)(wsb + (size_t)NQ * 2);
    const float*    biasT  = (const float*)(wsb + (size_t)(NQ + NP) * 2);
    const float*    bqkvF  = (const float*)(wsb + OFF_BQ);
    const float*    maskF  = (const float*)(wsb + OFF_MF);
    const float*    maskw  = mask + (size_t)(b % nW) * (NTOK * NTOK);
    const float*    maskFw = maskF + (size_t)(b % nW) * 4096;

    // ---------- Phase 0: x -> swizzled bf16 tile ----------
    {
        const float4* xb = (const float4*)(x + (size_t)b * (NTOK * DIM));
        for (int i = t; i < NTOK * DIM / 4; i += 512) {
            float4 v = xb[i];
            int e = i * 4, row = e / DIM, col = e - row * DIM;
            uint2 s;
            s.x = cvtpk_bf16(v.x, v.y);
            s.y = cvtpk_bf16(v.z, v.w);
            *(uint2*)&lds[U_OFF + swz(row, col)] = s;
        }
    }
    __syncthreads();   // S1

    // ---------- Phase A: typed passes, sched fences bound reg pressure ----------
    if (wave < 4) {
        phaseA_typed<2, 0, PM>(lds, wqkvP, w_qkv, bqkvF, b_qkv, wave,      lane, q4, l16);
        __builtin_amdgcn_sched_barrier(0);
        phaseA_typed<1, 1, PM>(lds, wqkvP, w_qkv, bqkvF, b_qkv, 16 + wave, lane, q4, l16);
        __builtin_amdgcn_sched_barrier(0);
        phaseA_typed<2, 2, PM>(lds, wqkvP, w_qkv, bqkvF, b_qkv, 24 + wave, lane, q4, l16);
    } else {
        phaseA_typed<1, 0, PM>(lds, wqkvP, w_qkv, bqkvF, b_qkv, wave,      lane, q4, l16);
        __builtin_amdgcn_sched_barrier(0);
        phaseA_typed<2, 1, PM>(lds, wqkvP, w_qkv, bqkvF, b_qkv, 8 + wave,  lane, q4, l16);
        __builtin_amdgcn_sched_barrier(0);
        phaseA_typed<1, 2, PM>(lds, wqkvP, w_qkv, bqkvF, b_qkv, 24 + wave, lane, q4, l16);
    }
    __syncthreads();   // S2

    // ---------- Phase B: attention (P^T softmax), zero barriers ----------
    const int mt    = wave & 3;
    const int hbase = (wave >> 2) * 3;
    uint16_t* paw = &lds[U_OFF + wave * (16 * PA_STR)];
    const int qt = mt * 16 + l16;
    const int qa = (qt < NTOK) ? qt : (NTOK - 1);

    f32x4 pacc[12];
    #pragma unroll
    for (int nt = 0; nt < 12; ++nt) pacc[nt] = (f32x4){0.f, 0.f, 0.f, 0.f};

    for (int hi = 0; hi < 3; ++hi) {
        const int h = hbase + hi;
        // --- QK^T swapped: lg[nt][i] = S[kt = nt*16+q4*4+i][qt = mt*16+l16] ---
        short8 bq = *(const short8*)&lds[QS_OFF + swz(qt, h * 32 + q4 * 8)];
        f32x4 lg[4];
        __builtin_amdgcn_s_setprio(1);
        #pragma unroll
        for (int nt = 0; nt < 4; ++nt) {
            short8 ak = *(const short8*)&lds[KS_OFF + swz(nt * 16 + l16, h * 32 + q4 * 8)];
            f32x4 z = (f32x4){0.f, 0.f, 0.f, 0.f};
            lg[nt] = __builtin_amdgcn_mfma_f32_16x16x32_bf16(ak, bq, z, 0, 0, 0);
        }
        __builtin_amdgcn_s_setprio(0);
        // --- + rel-pos bias + mask (both L2-resident tables for PM==2) ---
        #pragma unroll
        for (int nt = 0; nt < 4; ++nt) {
            if (PM == 2) {
                f32x4 bb = *(const f32x4*)&biasT[(((h * 4 + mt) * 4 + nt) * 64 + lane) * 4];
                f32x4 mm = *(const f32x4*)&maskFw[((mt * 4 + nt) * 64 + lane) * 4];
                #pragma unroll
                for (int i = 0; i < 4; ++i) lg[nt][i] += bb[i] + mm[i];
            } else if (PM == 1) {
                f32x4 bb = *(const f32x4*)&biasT[(((h * 4 + mt) * 4 + nt) * 64 + lane) * 4];
                #pragma unroll
                for (int i = 0; i < 4; ++i) {
                    int kt = nt * 16 + q4 * 4 + i;
                    int ka = (kt < NTOK) ? kt : (NTOK - 1);
                    lg[nt][i] += bb[i] + maskw[qa * NTOK + ka];
                }
            } else {
                #pragma unroll
                for (int i = 0; i < 4; ++i) {
                    int kt = nt * 16 + q4 * 4 + i;
                    int ka = (kt < NTOK) ? kt : (NTOK - 1);
                    int rm = qa % 7, rd = qa / 7, cm = ka % 7, cd = ka / 7;
                    int bi = 13 * (rm - cm + 6) + (rd - cd + 6);
                    lg[nt][i] += table[bi * NHEADS + h] + maskw[qa * NTOK + ka];
                }
            }
        }
        // --- softmax: row lane-local over regs + 2 shfls across q4 groups ---
        float m = lg[0][0];
        #pragma unroll
        for (int nt = 0; nt < 3; ++nt)
            #pragma unroll
            for (int i = 0; i < 4; ++i) m = fmaxf(m, lg[nt][i]);
        if (q4 == 0) m = fmaxf(m, lg[3][0]);      // kt == 48 only
        m = fmaxf(m, __shfl_xor(m, 16));
        m = fmaxf(m, __shfl_xor(m, 32));
        float s = 0.f;
        #pragma unroll
        for (int nt = 0; nt < 3; ++nt)
            #pragma unroll
            for (int i = 0; i < 4; ++i) { lg[nt][i] = __expf(lg[nt][i] - m); s += lg[nt][i]; }
        float e30 = (q4 == 0) ? __expf(lg[3][0] - m) : 0.f;   // zero kt>=49: no NaN leak
        s += e30;
        s += __shfl_xor(s, 16);
        s += __shfl_xor(s, 32);
        const float inv = 1.f / s;
        // --- pack P rows -> paw[qt_local][kt], b64 writes ---
        #pragma unroll
        for (int nt = 0; nt < 3; ++nt) {
            uint32_t lo = cvtpk_bf16(lg[nt][0] * inv, lg[nt][1] * inv);
            uint32_t hi = cvtpk_bf16(lg[nt][2] * inv, lg[nt][3] * inv);
            uint32_t* dst = (uint32_t*)&paw[l16 * PA_STR + nt * 16 + q4 * 4];
            dst[0] = lo; dst[1] = hi;
        }
        {
            uint32_t lo = cvtpk_bf16(e30 * inv, 0.f);
            uint32_t* dst = (uint32_t*)&paw[l16 * PA_STR + 48 + q4 * 4];
            dst[0] = lo; dst[1] = 0u;
        }
        asm volatile("" ::: "memory");   // in-order LDS within wave

        // --- PV: out tile 16x32 ---
        f32x4 ov[2];
        ov[0] = (f32x4){0.f, 0.f, 0.f, 0.f};
        ov[1] = (f32x4){0.f, 0.f, 0.f, 0.f};
        __builtin_amdgcn_s_setprio(1);
        #pragma unroll
        for (int kk = 0; kk < 2; ++kk) {
            short8 ap = *(const short8*)&paw[l16 * PA_STR + kk * 32 + q4 * 8];
            #pragma unroll
            for (int n2 = 0; n2 < 2; ++n2) {
                short8 bv = *(const short8*)&lds[VTA_OFF + vswz(h * 32 + n2 * 16 + l16,
                                                                kk * 32 + q4 * 8)];
                ov[n2] = __builtin_amdgcn_mfma_f32_16x16x32_bf16(ap, bv, ov[n2], 0, 0, 0);
            }
        }
        __builtin_amdgcn_s_setprio(0);
        // --- transpose out-tile through the same private scratch ---
        asm volatile("" ::: "memory");
        #pragma unroll
        for (int n2 = 0; n2 < 2; ++n2)
            #pragma unroll
            for (int i = 0; i < 4; ++i)
                paw[(q4 * 4 + i) * PA_STR + n2 * 16 + l16] = f2bf(ov[n2][i]);
        asm volatile("" ::: "memory");

        // --- proj partial: acc += os_h(16x32) @ wproj[h-slice](32x192) ---
        short8 ap2 = *(const short8*)&paw[l16 * PA_STR + q4 * 8];
        __builtin_amdgcn_s_setprio(1);
        #pragma unroll
        for (int nt = 0; nt < 12; ++nt) {
            short8 bw;
            if (PM >= 1) {
                bw = *(const short8*)&wprojP[(((size_t)(h * 12 + nt)) << 9) + (lane << 3)];
            } else {
                union { uint16_t u[8]; short8 v; } tb;
                int k0 = h * 32 + q4 * 8;
                #pragma unroll
                for (int j = 0; j < 8; ++j)
                    tb.u[j] = f2bf(w_proj[(size_t)(k0 + j) * DIM + nt * 16 + l16]);
                bw = tb.v;
            }
            pacc[nt] = __builtin_amdgcn_mfma_f32_16x16x32_bf16(ap2, bw, pacc[nt], 0, 0, 0);
        }
        __builtin_amdgcn_s_setprio(0);
    }
    __syncthreads();   // S3: all tasks done; qs/ks/vta/pa dead

    // ---------- Phase C: cross-wave-pair reduction + writeout ----------
    float* R = (float*)lds;
    if (wave >= 4) {
        float* rw = R + (size_t)(mt * 64 + lane) * R_STR;
        #pragma unroll
        for (int nt = 0; nt < 12; ++nt)
            *(f32x4*)(rw + nt * 4) = pacc[nt];
    }
    __syncthreads();   // S4
    if (wave < 4) {
        const float* rr = R + (size_t)(mt * 64 + lane) * R_STR;
        float* ob = out + (size_t)b * (NTOK * DIM);
        #pragma unroll
        for (int nt = 0; nt < 12; ++nt) {
            f32x4 other = *(const f32x4*)(rr + nt * 4);
            const int c = nt * 16 + l16;
            const float bp = b_proj[c];
            #pragma unroll
            for (int i = 0; i < 4; ++i) {
                const int r = mt * 16 + q4 * 4 + i;
                if (r < NTOK) ob[r * DIM + c] = pacc[nt][i] + other[i] + bp;
            }
        }
    }
}

extern "C" void kernel_launch(void* const* d_in, const int* in_sizes, int n_in,
                              void* d_out, int out_size, void* d_ws, size_t ws_size,
                              hipStream_t stream) {
    const float* x      = (const float*)d_in[0];
    const float* mask   = (const float*)d_in[1];
    const float* w_qkv  = (const float*)d_in[2];
    const float* b_qkv  = (const float*)d_in[3];
    const float* w_proj = (const float*)d_in[4];
    const float* b_proj = (const float*)d_in[5];
    const float* table  = (const float*)d_in[6];
    float* out = (float*)d_out;

    const int nblocks = in_sizes[0] / (NTOK * DIM);   // 4096 windows
    const int nW      = in_sizes[1] / (NTOK * NTOK);  // 64
    const size_t NEED1 = OFF_MF;                          // base + bqkvF
    const size_t NEED2 = OFF_MF + (size_t)nW * 4096 * 4;  // + maskF

    if (d_ws != nullptr && ws_size >= NEED2) {
        uint8_t* wsb = (uint8_t*)d_ws;
        const int nmask = nW * 4096;
        const int total = NQ + NP + NB + 576 + nmask;
        prep_all<<<(total + 255) / 256, 256, 0, stream>>>(w_qkv, w_proj, table,
                                                          b_qkv, mask, nmask, wsb);
        winattn_mfma6<2><<<nblocks, 512, 0, stream>>>(x, mask, nW, w_qkv, b_qkv,
                                                      w_proj, b_proj, table, wsb, out);
    } else if (d_ws != nullptr && ws_size >= NEED1) {
        uint8_t* wsb = (uint8_t*)d_ws;
        const int total = NQ + NP + NB + 576;
        prep_all<<<(total + 255) / 256, 256, 0, stream>>>(w_qkv, w_proj, table,
                                                          b_qkv, mask, 0, wsb);
        winattn_mfma6<1><<<nblocks, 512, 0, stream>>>(x, mask, nW, w_qkv, b_qkv,
                                                      w_proj, b_proj, table, wsb, out);
    } else {
        winattn_mfma6<0><<<nblocks, 512, 0, stream>>>(x, mask, nW, w_qkv, b_qkv,
                                                      w_proj, b_proj, table, nullptr, out);
    }
}